// Round 1
// baseline (926.696 us; speedup 1.0000x reference)
//
#include <hip/hip_runtime.h>
#include <hip/hip_bf16.h>
#include <math.h>

#define B_G   128
#define N0    512
#define DEG   8
#define CCH   128
#define E_TOTAL (B_G*N0*DEG)
#define K1    410
#define K2    328
#define K3    263
#define NCLS  10

// ---------------- init ----------------
__global__ void init_edges(const int* __restrict__ es, const int* __restrict__ ed,
                           int* __restrict__ cs, int* __restrict__ cd,
                           unsigned char* __restrict__ valid, float* __restrict__ g) {
    int e = blockIdx.x * 256 + threadIdx.x;
    if (e < E_TOTAL) { cs[e] = es[e]; cd[e] = ed[e]; valid[e] = 1; }
    if (e < B_G * 256) g[e] = 0.f;
}

__global__ void memset_i32(int* __restrict__ p, int v, int n) {
    int i = blockIdx.x * 256 + threadIdx.x;
    if (i < n) p[i] = v;
}

// ---------------- CSR build ----------------
__global__ void count_edges(const int* __restrict__ dst, const unsigned char* __restrict__ valid,
                            int* __restrict__ counts) {
    int e = blockIdx.x * 256 + threadIdx.x;
    if (e < E_TOTAL && valid[e]) atomicAdd(&counts[dst[e]], 1);
}

__global__ __launch_bounds__(1024) void scan_counts(const int* __restrict__ counts,
                                                    int* __restrict__ indptr,
                                                    int* __restrict__ cursor, int n) {
    __shared__ int part[1024];
    int tid = threadIdx.x;
    int chunk = (((n + 1023) >> 10) + 3) & ~3;   // mult of 4; n is mult of 4
    int start = tid * chunk;
    int s = 0;
    for (int t = 0; t < chunk; t += 4) {
        int i = start + t;
        if (i < n) { int4 v = *(const int4*)&counts[i]; s += v.x + v.y + v.z + v.w; }
    }
    part[tid] = s; __syncthreads();
    for (int off = 1; off < 1024; off <<= 1) {
        int v = (tid >= off) ? part[tid - off] : 0;
        __syncthreads();
        part[tid] += v; __syncthreads();
    }
    int run = tid ? part[tid - 1] : 0;
    for (int t = 0; t < chunk; t++) {
        int i = start + t;
        if (i < n) { int c = counts[i]; indptr[i] = run; cursor[i] = run; run += c; }
    }
    if (tid == 1023) indptr[n] = part[1023];
}

__global__ void fill_srclist(const int* __restrict__ src, const int* __restrict__ dst,
                             const unsigned char* __restrict__ valid,
                             int* __restrict__ cursor, int* __restrict__ srclist) {
    int e = blockIdx.x * 256 + threadIdx.x;
    if (e < E_TOTAL && valid[e]) {
        int pos = atomicAdd(&cursor[dst[e]], 1);
        srclist[pos] = src[e];
    }
}

// ---------------- aggregation: one wave per dst node ----------------
__global__ void aggregate(const float* __restrict__ x, const int* __restrict__ indptr,
                          const int* __restrict__ srclist, float* __restrict__ agg, int n_nodes) {
    int wid = (blockIdx.x * 256 + threadIdx.x) >> 6;
    int lane = threadIdx.x & 63;
    if (wid >= n_nodes) return;
    float a0 = 0.f, a1 = 0.f;
    int beg = indptr[wid], end = indptr[wid + 1];
    for (int j = beg; j < end; j++) {
        int s = srclist[j];
        const float* r = x + (size_t)s * CCH;
        a0 += r[lane]; a1 += r[64 + lane];
    }
    agg[(size_t)wid * CCH + lane] = a0;
    agg[(size_t)wid * CCH + 64 + lane] = a1;
}

// ---------------- fused transform: out = relu(agg@Wrel + x@Wroot + brel) ----------------
// block: 256 threads, 64 rows x 128 cols, K=256 (two halves of 128)
__global__ __launch_bounds__(256) void transform(
        const float* __restrict__ agg, const float* __restrict__ x,
        const float* __restrict__ Wrel, const float* __restrict__ Wroot,
        const float* __restrict__ brel, float* __restrict__ out, int M) {
    __shared__ float Bs[128 * 128];      // 64 KB, current weight matrix
    __shared__ float As[64 * 33];        // 8.4 KB, A chunk [64 rows][32 k], padded
    int tid = threadIdx.x;
    int tc = tid & 15, tr = tid >> 4;
    int c0 = tc * 8, r0 = tr * 4;
    int rows0 = blockIdx.x * 64;

    float acc[4][8];
#pragma unroll
    for (int m = 0; m < 4; m++)
#pragma unroll
        for (int n = 0; n < 8; n++) acc[m][n] = 0.f;

    for (int h = 0; h < 2; h++) {
        const float* W = h ? Wroot : Wrel;
        const float* A = h ? x : agg;
        // load weights into LDS
        float4* Bs4 = (float4*)Bs;
        const float4* W4 = (const float4*)W;
#pragma unroll
        for (int i = 0; i < 16; i++) Bs4[tid + i * 256] = W4[tid + i * 256];
        __syncthreads();
        for (int kc = 0; kc < 4; kc++) {
            // stage A chunk: 64 rows x 32 k
            {
                int e0 = tid * 8;
                int r = e0 >> 5, kk0 = e0 & 31;
                const float4* s4 = (const float4*)&A[(size_t)(rows0 + r) * CCH + kc * 32 + kk0];
                float4 v0 = s4[0], v1 = s4[1];
                float* d = &As[r * 33 + kk0];
                d[0] = v0.x; d[1] = v0.y; d[2] = v0.z; d[3] = v0.w;
                d[4] = v1.x; d[5] = v1.y; d[6] = v1.z; d[7] = v1.w;
            }
            __syncthreads();
#pragma unroll 8
            for (int kk = 0; kk < 32; kk++) {
                const float* bp = &Bs[(kc * 32 + kk) * 128 + c0];
                float bv[8];
                float4 bA = *(const float4*)bp;
                float4 bB = *(const float4*)(bp + 4);
                bv[0] = bA.x; bv[1] = bA.y; bv[2] = bA.z; bv[3] = bA.w;
                bv[4] = bB.x; bv[5] = bB.y; bv[6] = bB.z; bv[7] = bB.w;
                float av[4];
#pragma unroll
                for (int m = 0; m < 4; m++) av[m] = As[(r0 + m) * 33 + kk];
#pragma unroll
                for (int m = 0; m < 4; m++)
#pragma unroll
                    for (int n = 0; n < 8; n++) acc[m][n] += av[m] * bv[n];
            }
            __syncthreads();
        }
    }
    // epilogue
    float4 br0 = *(const float4*)&brel[c0];
    float4 br1 = *(const float4*)&brel[c0 + 4];
    float bb[8] = {br0.x, br0.y, br0.z, br0.w, br1.x, br1.y, br1.z, br1.w};
#pragma unroll
    for (int m = 0; m < 4; m++) {
        int row = rows0 + r0 + m;
        float o[8];
#pragma unroll
        for (int n = 0; n < 8; n++) {
            float v = acc[m][n] + bb[n];
            o[n] = v > 0.f ? v : 0.f;
        }
        float4* op = (float4*)&out[(size_t)row * CCH + c0];
        op[0] = make_float4(o[0], o[1], o[2], o[3]);
        op[1] = make_float4(o[4], o[5], o[6], o[7]);
    }
}

// ---------------- scores: tanh(x.p/||p||), one wave per node ----------------
__global__ void score_kernel(const float* __restrict__ x, const float* __restrict__ p,
                             float* __restrict__ score, int n_nodes) {
    int wid = (blockIdx.x * 256 + threadIdx.x) >> 6;
    int lane = threadIdx.x & 63;
    if (wid >= n_nodes) return;
    float p0 = p[lane], p1 = p[64 + lane];
    float d = x[(size_t)wid * CCH + lane] * p0 + x[(size_t)wid * CCH + 64 + lane] * p1;
    float q = p0 * p0 + p1 * p1;
    for (int off = 32; off; off >>= 1) {
        d += __shfl_xor(d, off);
        q += __shfl_xor(q, off);
    }
    if (lane == 0) score[wid] = tanhf(d / sqrtf(q));
}

// ---------------- top-k per graph: bitonic sort of 512 packed keys ----------------
__global__ __launch_bounds__(256) void topk_kernel(const float* __restrict__ score,
                                                   int* __restrict__ inv,
                                                   int* __restrict__ kglob,
                                                   float* __restrict__ kval, int n, int k) {
    int b = blockIdx.x;
    __shared__ unsigned long long keys[512];
    int tid = threadIdx.x;
    for (int s = tid; s < 512; s += 256) {
        unsigned long long key = 0ull;   // sorts below all real scores
        if (s < n) {
            float v = score[b * n + s];
            unsigned u = __float_as_uint(v);
            u = (u & 0x80000000u) ? ~u : (u | 0x80000000u);   // orderable
            key = ((unsigned long long)u << 32) | (unsigned)(~s); // ties -> lower idx first
        }
        keys[s] = key;
    }
    __syncthreads();
    for (int kk2 = 2; kk2 <= 512; kk2 <<= 1) {
        for (int j = kk2 >> 1; j > 0; j >>= 1) {
            for (int s = tid; s < 512; s += 256) {
                int sxj = s ^ j;
                if (sxj > s) {
                    unsigned long long a = keys[s], c = keys[sxj];
                    bool descRegion = ((s & kk2) == 0);
                    bool doSwap = descRegion ? (a < c) : (a > c);
                    if (doSwap) { keys[s] = c; keys[sxj] = a; }
                }
            }
            __syncthreads();
        }
    }
    for (int j = tid; j < k; j += 256) {
        unsigned long long key = keys[j];
        int node = (int)(~(unsigned)key);
        float v = score[b * n + node];
        int newid = b * k + j;
        kglob[newid] = b * n + node;
        kval[newid] = v;
        inv[b * n + node] = newid;
    }
}

// ---------------- gather+scale kept rows ----------------
__global__ void gather_kernel(const float* __restrict__ xold, const int* __restrict__ kglob,
                              const float* __restrict__ kval, float* __restrict__ xnew, int nk) {
    int wid = (blockIdx.x * 256 + threadIdx.x) >> 6;
    int lane = threadIdx.x & 63;
    if (wid >= nk) return;
    int gsrc = kglob[wid];
    float v = kval[wid];
    xnew[(size_t)wid * CCH + lane] = xold[(size_t)gsrc * CCH + lane] * v;
    xnew[(size_t)wid * CCH + 64 + lane] = xold[(size_t)gsrc * CCH + 64 + lane] * v;
}

// ---------------- remap edges through inv ----------------
__global__ void remap_edges(int* __restrict__ src, int* __restrict__ dst,
                            unsigned char* __restrict__ valid, const int* __restrict__ inv) {
    int e = blockIdx.x * 256 + threadIdx.x;
    if (e >= E_TOTAL) return;
    if (!valid[e]) return;
    int s = inv[src[e]], d = inv[dst[e]];
    if ((s | d) < 0) { valid[e] = 0; }
    else { src[e] = s; dst[e] = d; }
}

// ---------------- readout: gmp || gap, accumulated into g ----------------
__global__ __launch_bounds__(512) void readout_kernel(const float* __restrict__ x,
                                                      float* __restrict__ g, int k) {
    int b = blockIdx.x;
    int c = threadIdx.x & 127;
    int q = threadIdx.x >> 7;
    float mx = -1e30f, sm = 0.f;
    for (int j = q; j < k; j += 4) {
        float v = x[((size_t)b * k + j) * CCH + c];
        mx = fmaxf(mx, v); sm += v;
    }
    __shared__ float smx[4][128], ssm[4][128];
    smx[q][c] = mx; ssm[q][c] = sm;
    __syncthreads();
    if (q == 0) {
        mx = fmaxf(fmaxf(smx[0][c], smx[1][c]), fmaxf(smx[2][c], smx[3][c]));
        sm = ssm[0][c] + ssm[1][c] + ssm[2][c] + ssm[3][c];
        g[b * 256 + c] += mx;
        g[b * 256 + 128 + c] += sm / (float)k;
    }
}

// ---------------- final MLP + log_softmax ----------------
__global__ __launch_bounds__(128) void mlp_kernel(const float* __restrict__ g,
        const float* __restrict__ W1, const float* __restrict__ b1,
        const float* __restrict__ W2, const float* __restrict__ b2,
        const float* __restrict__ W3, const float* __restrict__ b3,
        float* __restrict__ out) {
    int b = blockIdx.x, t = threadIdx.x;
    __shared__ float gs[256], h1[128], h2[64], lg[10];
    gs[t] = g[b * 256 + t];
    gs[128 + t] = g[b * 256 + 128 + t];
    __syncthreads();
    {
        float a = b1[t];
        for (int c = 0; c < 256; c++) a += gs[c] * W1[c * 128 + t];
        h1[t] = fmaxf(a, 0.f);
    }
    __syncthreads();
    if (t < 64) {
        float a = b2[t];
        for (int c = 0; c < 128; c++) a += h1[c] * W2[c * 64 + t];
        h2[t] = fmaxf(a, 0.f);
    }
    __syncthreads();
    if (t < 10) {
        float a = b3[t];
        for (int c = 0; c < 64; c++) a += h2[c] * W3[c * 10 + t];
        lg[t] = a;
    }
    __syncthreads();
    if (t < 10) {
        float m = lg[0];
        for (int i = 1; i < 10; i++) m = fmaxf(m, lg[i]);
        float s = 0.f;
        for (int i = 0; i < 10; i++) s += expf(lg[i] - m);
        out[b * 10 + t] = lg[t] - m - logf(s);
    }
}

// ---------------- host ----------------
extern "C" void kernel_launch(void* const* d_in, const int* in_sizes, int n_in,
                              void* d_out, int out_size, void* d_ws, size_t ws_size,
                              hipStream_t stream) {
    (void)in_sizes; (void)n_in; (void)out_size; (void)ws_size;
    const float* x0 = (const float*)d_in[0];
    const int* es = (const int*)d_in[1];
    const int* ed = (const int*)d_in[2];
    const float* Wroot[3] = {(const float*)d_in[3], (const float*)d_in[7], (const float*)d_in[11]};
    const float* Wrel[3]  = {(const float*)d_in[4], (const float*)d_in[8], (const float*)d_in[12]};
    const float* brel[3]  = {(const float*)d_in[5], (const float*)d_in[9], (const float*)d_in[13]};
    const float* pvec[3]  = {(const float*)d_in[6], (const float*)d_in[10], (const float*)d_in[14]};
    const float* W1 = (const float*)d_in[15];
    const float* b1 = (const float*)d_in[16];
    const float* W2 = (const float*)d_in[17];
    const float* b2 = (const float*)d_in[18];
    const float* W3 = (const float*)d_in[19];
    const float* b3 = (const float*)d_in[20];

    size_t off = 0;
    char* base = (char*)d_ws;
    auto alloc = [&](size_t bytes) -> void* {
        void* p = base + off;
        off += (bytes + 255) & ~(size_t)255;
        return p;
    };
    float* bufA = (float*)alloc((size_t)(B_G * N0) * CCH * 4);   // agg / h (in-place)
    float* bufX = (float*)alloc((size_t)(B_G * K1) * CCH * 4);   // pooled x
    int* cur_src = (int*)alloc((size_t)E_TOTAL * 4);
    int* cur_dst = (int*)alloc((size_t)E_TOTAL * 4);
    unsigned char* valid = (unsigned char*)alloc(E_TOTAL);
    int* counts = (int*)alloc((size_t)(B_G * N0 + 1) * 4);
    int* indptr = (int*)alloc((size_t)(B_G * N0 + 1) * 4);
    int* cursor = (int*)alloc((size_t)(B_G * N0 + 1) * 4);
    int* srclist = (int*)alloc((size_t)E_TOTAL * 4);
    float* score = (float*)alloc((size_t)(B_G * N0) * 4);
    int* inv = (int*)alloc((size_t)(B_G * N0) * 4);
    int* kglob = (int*)alloc((size_t)(B_G * K1) * 4);
    float* kval = (float*)alloc((size_t)(B_G * K1) * 4);
    float* g = (float*)alloc((size_t)B_G * 256 * 4);

    const int EGRID = (E_TOTAL + 255) / 256;
    init_edges<<<EGRID, 256, 0, stream>>>(es, ed, cur_src, cur_dst, valid, g);

    int nper[4] = {N0, K1, K2, K3};
    const float* xin = x0;
    for (int l = 0; l < 3; l++) {
        int n = nper[l], k = nper[l + 1];
        int n_nodes = B_G * n;
        int nk = B_G * k;
        // CSR by dst
        memset_i32<<<(n_nodes + 255) / 256, 256, 0, stream>>>(counts, 0, n_nodes);
        count_edges<<<EGRID, 256, 0, stream>>>(cur_dst, valid, counts);
        scan_counts<<<1, 1024, 0, stream>>>(counts, indptr, cursor, n_nodes);
        fill_srclist<<<EGRID, 256, 0, stream>>>(cur_src, cur_dst, valid, cursor, srclist);
        // conv
        aggregate<<<n_nodes / 4, 256, 0, stream>>>(xin, indptr, srclist, bufA, n_nodes);
        transform<<<n_nodes / 64, 256, 0, stream>>>(bufA, xin, Wrel[l], Wroot[l], brel[l], bufA, n_nodes);
        // pool
        score_kernel<<<n_nodes / 4, 256, 0, stream>>>(bufA, pvec[l], score, n_nodes);
        memset_i32<<<(n_nodes + 255) / 256, 256, 0, stream>>>(inv, -1, n_nodes);
        topk_kernel<<<B_G, 256, 0, stream>>>(score, inv, kglob, kval, n, k);
        gather_kernel<<<(nk + 3) / 4, 256, 0, stream>>>(bufA, kglob, kval, bufX, nk);
        if (l < 2) remap_edges<<<EGRID, 256, 0, stream>>>(cur_src, cur_dst, valid, inv);
        readout_kernel<<<B_G, 512, 0, stream>>>(bufX, g, k);
        xin = bufX;
    }
    mlp_kernel<<<B_G, 128, 0, stream>>>(g, W1, b1, W2, b2, W3, b3, (float*)d_out);
}

// Round 2
// 578.527 us; speedup vs baseline: 1.6018x; 1.6018x over previous
//
#include <hip/hip_runtime.h>
#include <hip/hip_bf16.h>
#include <math.h>

#define B_G   128
#define N0    512
#define DEG   8
#define CCH   128
#define EPG   (N0*DEG)            // 4096 edges per graph (fixed slab)
#define E_TOTAL (B_G*EPG)
#define K1    410
#define K2    328
#define K3    263
#define NCLS  10

// ---------------- init: copy edges, valid=1, zero g, zero counts, inv=-1 ----------------
__global__ void init_all(const int* __restrict__ es, const int* __restrict__ ed,
                         int* __restrict__ cs, int* __restrict__ cd,
                         unsigned char* __restrict__ valid, float* __restrict__ g,
                         int* __restrict__ counts, int* __restrict__ inv) {
    int e = blockIdx.x * 256 + threadIdx.x;
    if (e < E_TOTAL) { cs[e] = es[e]; cd[e] = ed[e]; valid[e] = 1; }
    if (e < B_G * N0) { counts[e] = 0; inv[e] = -1; }
    if (e < B_G * 256) g[e] = 0.f;
}

// ---------------- layer-0 edge count ----------------
__global__ void count_edges(const int* __restrict__ dst, const unsigned char* __restrict__ valid,
                            int* __restrict__ counts) {
    int e = blockIdx.x * 256 + threadIdx.x;
    if (e < E_TOTAL && valid[e]) atomicAdd(&counts[dst[e]], 1);
}

// ---------------- per-graph exclusive scan (n <= 512), one block per graph ----------------
__global__ __launch_bounds__(512) void scan_graph(const int* __restrict__ counts,
                                                  int* __restrict__ indptr,
                                                  int* __restrict__ cursor, int n) {
    int b = blockIdx.x, tid = threadIdx.x;
    __shared__ int s[512];
    s[tid] = (tid < n) ? counts[b * n + tid] : 0;
    __syncthreads();
    for (int off = 1; off < 512; off <<= 1) {
        int v = (tid >= off) ? s[tid - off] : 0;
        __syncthreads();
        s[tid] += v;
        __syncthreads();
    }
    if (tid < n) {
        int pre = tid ? s[tid - 1] : 0;
        int ip = b * EPG + pre;
        indptr[b * n + tid] = ip;
        cursor[b * n + tid] = ip;
    }
}

__global__ void fill_srclist(const int* __restrict__ src, const int* __restrict__ dst,
                             const unsigned char* __restrict__ valid,
                             int* __restrict__ cursor, int* __restrict__ srclist) {
    int e = blockIdx.x * 256 + threadIdx.x;
    if (e < E_TOTAL && valid[e]) {
        int pos = atomicAdd(&cursor[dst[e]], 1);
        srclist[pos] = src[e];
    }
}

// ---------------- aggregation: one wave per dst node ----------------
__global__ void aggregate(const float* __restrict__ x, const int* __restrict__ indptr,
                          const int* __restrict__ counts, const int* __restrict__ srclist,
                          float* __restrict__ agg, int n_nodes) {
    int wid = (blockIdx.x * 256 + threadIdx.x) >> 6;
    int lane = threadIdx.x & 63;
    if (wid >= n_nodes) return;
    float a0 = 0.f, a1 = 0.f;
    int beg = indptr[wid], end = beg + counts[wid];
    for (int j = beg; j < end; j++) {
        int s = srclist[j];
        const float* r = x + (size_t)s * CCH;
        a0 += r[lane]; a1 += r[64 + lane];
    }
    agg[(size_t)wid * CCH + lane] = a0;
    agg[(size_t)wid * CCH + 64 + lane] = a1;
}

// ---------------- fused transform + score:
//   h = relu(agg@Wrel + x@Wroot + brel);  score = tanh(h.p/||p||)
__global__ __launch_bounds__(256) void transform(
        const float* __restrict__ agg, const float* __restrict__ x,
        const float* __restrict__ Wrel, const float* __restrict__ Wroot,
        const float* __restrict__ brel, const float* __restrict__ p,
        float* __restrict__ out, float* __restrict__ score) {
    __shared__ float Bs[128 * 128];      // 64 KB, current weight matrix
    __shared__ float As[64 * 33];        // A chunk [64 rows][32 k], padded
    int tid = threadIdx.x;
    int tc = tid & 15, tr = tid >> 4;
    int c0 = tc * 8, r0 = tr * 4;
    int rows0 = blockIdx.x * 64;

    float acc[4][8];
#pragma unroll
    for (int m = 0; m < 4; m++)
#pragma unroll
        for (int n = 0; n < 8; n++) acc[m][n] = 0.f;

    for (int h = 0; h < 2; h++) {
        const float* W = h ? Wroot : Wrel;
        const float* A = h ? x : agg;
        float4* Bs4 = (float4*)Bs;
        const float4* W4 = (const float4*)W;
#pragma unroll
        for (int i = 0; i < 16; i++) Bs4[tid + i * 256] = W4[tid + i * 256];
        __syncthreads();
        for (int kc = 0; kc < 4; kc++) {
            {
                int e0 = tid * 8;
                int r = e0 >> 5, kk0 = e0 & 31;
                const float4* s4 = (const float4*)&A[(size_t)(rows0 + r) * CCH + kc * 32 + kk0];
                float4 v0 = s4[0], v1 = s4[1];
                float* d = &As[r * 33 + kk0];
                d[0] = v0.x; d[1] = v0.y; d[2] = v0.z; d[3] = v0.w;
                d[4] = v1.x; d[5] = v1.y; d[6] = v1.z; d[7] = v1.w;
            }
            __syncthreads();
#pragma unroll 8
            for (int kk = 0; kk < 32; kk++) {
                const float* bp = &Bs[(kc * 32 + kk) * 128 + c0];
                float bv[8];
                float4 bA = *(const float4*)bp;
                float4 bB = *(const float4*)(bp + 4);
                bv[0] = bA.x; bv[1] = bA.y; bv[2] = bA.z; bv[3] = bA.w;
                bv[4] = bB.x; bv[5] = bB.y; bv[6] = bB.z; bv[7] = bB.w;
                float av[4];
#pragma unroll
                for (int m = 0; m < 4; m++) av[m] = As[(r0 + m) * 33 + kk];
#pragma unroll
                for (int m = 0; m < 4; m++)
#pragma unroll
                    for (int n = 0; n < 8; n++) acc[m][n] += av[m] * bv[n];
            }
            __syncthreads();
        }
    }
    // epilogue: bias + relu, store, fused score
    float4 br0 = *(const float4*)&brel[c0];
    float4 br1 = *(const float4*)&brel[c0 + 4];
    float bb[8] = {br0.x, br0.y, br0.z, br0.w, br1.x, br1.y, br1.z, br1.w};
    float4 pv0 = *(const float4*)&p[c0];
    float4 pv1 = *(const float4*)&p[c0 + 4];
    float pv[8] = {pv0.x, pv0.y, pv0.z, pv0.w, pv1.x, pv1.y, pv1.z, pv1.w};
    float q = 0.f;
#pragma unroll
    for (int n = 0; n < 8; n++) q += pv[n] * pv[n];
    float dots[4];
#pragma unroll
    for (int m = 0; m < 4; m++) {
        int row = rows0 + r0 + m;
        float d = 0.f;
#pragma unroll
        for (int n = 0; n < 8; n++) {
            float v = acc[m][n] + bb[n];
            v = v > 0.f ? v : 0.f;
            acc[m][n] = v;
            d += v * pv[n];
        }
        dots[m] = d;
        float4* op = (float4*)&out[(size_t)row * CCH + c0];
        op[0] = make_float4(acc[m][0], acc[m][1], acc[m][2], acc[m][3]);
        op[1] = make_float4(acc[m][4], acc[m][5], acc[m][6], acc[m][7]);
    }
    // reduce q and dots over the 16 lanes of this row group (lanes are 16-aligned in wave)
#pragma unroll
    for (int off = 1; off < 16; off <<= 1) {
        q += __shfl_xor(q, off);
#pragma unroll
        for (int m = 0; m < 4; m++) dots[m] += __shfl_xor(dots[m], off);
    }
    if (tc == 0) {
        float inv_norm = rsqrtf(q);
#pragma unroll
        for (int m = 0; m < 4; m++)
            score[rows0 + r0 + m] = tanhf(dots[m] * inv_norm);
    }
}

// ---------------- top-k per graph: bitonic sort of 512 packed keys ----------------
__global__ __launch_bounds__(256) void topk_kernel(const float* __restrict__ score,
                                                   int* __restrict__ inv,
                                                   int* __restrict__ kglob,
                                                   float* __restrict__ kval, int n, int k) {
    int b = blockIdx.x;
    __shared__ unsigned long long keys[512];
    int tid = threadIdx.x;
    for (int s = tid; s < 512; s += 256) {
        unsigned long long key = 0ull;   // sorts below all real scores
        if (s < n) {
            float v = score[b * n + s];
            unsigned u = __float_as_uint(v);
            u = (u & 0x80000000u) ? ~u : (u | 0x80000000u);   // orderable
            key = ((unsigned long long)u << 32) | (unsigned)(~s); // ties -> lower idx first
        }
        keys[s] = key;
    }
    __syncthreads();
    for (int kk2 = 2; kk2 <= 512; kk2 <<= 1) {
        for (int j = kk2 >> 1; j > 0; j >>= 1) {
            for (int s = tid; s < 512; s += 256) {
                int sxj = s ^ j;
                if (sxj > s) {
                    unsigned long long a = keys[s], c = keys[sxj];
                    bool descRegion = ((s & kk2) == 0);
                    bool doSwap = descRegion ? (a < c) : (a > c);
                    if (doSwap) { keys[s] = c; keys[sxj] = a; }
                }
            }
            __syncthreads();
        }
    }
    for (int j = tid; j < k; j += 256) {
        unsigned long long key = keys[j];
        int node = (int)(~(unsigned)key);
        float v = score[b * n + node];
        int newid = b * k + j;
        kglob[newid] = b * n + node;
        kval[newid] = v;
        inv[b * n + node] = newid;
    }
}

// ---------------- gather+scale kept rows ----------------
__global__ void gather_kernel(const float* __restrict__ xold, const int* __restrict__ kglob,
                              const float* __restrict__ kval, float* __restrict__ xnew, int nk) {
    int wid = (blockIdx.x * 256 + threadIdx.x) >> 6;
    int lane = threadIdx.x & 63;
    if (wid >= nk) return;
    int gsrc = kglob[wid];
    float v = kval[wid];
    xnew[(size_t)wid * CCH + lane] = xold[(size_t)gsrc * CCH + lane] * v;
    xnew[(size_t)wid * CCH + 64 + lane] = xold[(size_t)gsrc * CCH + 64 + lane] * v;
}

// ---------------- prep next layer: zero counts, inv=-1 ----------------
__global__ void prep_next(int* __restrict__ counts, int* __restrict__ inv, int n) {
    int i = blockIdx.x * 256 + threadIdx.x;
    if (i < n) { counts[i] = 0; inv[i] = -1; }
}

// ---------------- fused remap edges + count for next layer ----------------
__global__ void remap_count(int* __restrict__ src, int* __restrict__ dst,
                            unsigned char* __restrict__ valid, const int* __restrict__ inv,
                            int* __restrict__ counts) {
    int e = blockIdx.x * 256 + threadIdx.x;
    if (e >= E_TOTAL) return;
    if (!valid[e]) return;
    int s = inv[src[e]], d = inv[dst[e]];
    if ((s | d) < 0) { valid[e] = 0; }
    else { src[e] = s; dst[e] = d; atomicAdd(&counts[d], 1); }
}

// ---------------- readout: gmp || gap, accumulated into g ----------------
__global__ __launch_bounds__(512) void readout_kernel(const float* __restrict__ x,
                                                      float* __restrict__ g, int k) {
    int b = blockIdx.x;
    int c = threadIdx.x & 127;
    int q = threadIdx.x >> 7;
    float mx = -1e30f, sm = 0.f;
    for (int j = q; j < k; j += 4) {
        float v = x[((size_t)b * k + j) * CCH + c];
        mx = fmaxf(mx, v); sm += v;
    }
    __shared__ float smx[4][128], ssm[4][128];
    smx[q][c] = mx; ssm[q][c] = sm;
    __syncthreads();
    if (q == 0) {
        mx = fmaxf(fmaxf(smx[0][c], smx[1][c]), fmaxf(smx[2][c], smx[3][c]));
        sm = ssm[0][c] + ssm[1][c] + ssm[2][c] + ssm[3][c];
        g[b * 256 + c] += mx;
        g[b * 256 + 128 + c] += sm / (float)k;
    }
}

// ---------------- final MLP + log_softmax ----------------
__global__ __launch_bounds__(128) void mlp_kernel(const float* __restrict__ g,
        const float* __restrict__ W1, const float* __restrict__ b1,
        const float* __restrict__ W2, const float* __restrict__ b2,
        const float* __restrict__ W3, const float* __restrict__ b3,
        float* __restrict__ out) {
    int b = blockIdx.x, t = threadIdx.x;
    __shared__ float gs[256], h1[128], h2[64], lg[10];
    gs[t] = g[b * 256 + t];
    gs[128 + t] = g[b * 256 + 128 + t];
    __syncthreads();
    {
        float a = b1[t];
        for (int c = 0; c < 256; c++) a += gs[c] * W1[c * 128 + t];
        h1[t] = fmaxf(a, 0.f);
    }
    __syncthreads();
    if (t < 64) {
        float a = b2[t];
        for (int c = 0; c < 128; c++) a += h1[c] * W2[c * 64 + t];
        h2[t] = fmaxf(a, 0.f);
    }
    __syncthreads();
    if (t < 10) {
        float a = b3[t];
        for (int c = 0; c < 64; c++) a += h2[c] * W3[c * 10 + t];
        lg[t] = a;
    }
    __syncthreads();
    if (t < 10) {
        float m = lg[0];
        for (int i = 1; i < 10; i++) m = fmaxf(m, lg[i]);
        float s = 0.f;
        for (int i = 0; i < 10; i++) s += expf(lg[i] - m);
        out[b * 10 + t] = lg[t] - m - logf(s);
    }
}

// ---------------- host ----------------
extern "C" void kernel_launch(void* const* d_in, const int* in_sizes, int n_in,
                              void* d_out, int out_size, void* d_ws, size_t ws_size,
                              hipStream_t stream) {
    (void)in_sizes; (void)n_in; (void)out_size; (void)ws_size;
    const float* x0 = (const float*)d_in[0];
    const int* es = (const int*)d_in[1];
    const int* ed = (const int*)d_in[2];
    const float* Wroot[3] = {(const float*)d_in[3], (const float*)d_in[7], (const float*)d_in[11]};
    const float* Wrel[3]  = {(const float*)d_in[4], (const float*)d_in[8], (const float*)d_in[12]};
    const float* brel[3]  = {(const float*)d_in[5], (const float*)d_in[9], (const float*)d_in[13]};
    const float* pvec[3]  = {(const float*)d_in[6], (const float*)d_in[10], (const float*)d_in[14]};
    const float* W1 = (const float*)d_in[15];
    const float* b1 = (const float*)d_in[16];
    const float* W2 = (const float*)d_in[17];
    const float* b2 = (const float*)d_in[18];
    const float* W3 = (const float*)d_in[19];
    const float* b3 = (const float*)d_in[20];

    size_t off = 0;
    char* base = (char*)d_ws;
    auto alloc = [&](size_t bytes) -> void* {
        void* p = base + off;
        off += (bytes + 255) & ~(size_t)255;
        return p;
    };
    float* bufA = (float*)alloc((size_t)(B_G * N0) * CCH * 4);   // agg / h (in-place)
    float* bufX = (float*)alloc((size_t)(B_G * K1) * CCH * 4);   // pooled x
    int* cur_src = (int*)alloc((size_t)E_TOTAL * 4);
    int* cur_dst = (int*)alloc((size_t)E_TOTAL * 4);
    unsigned char* valid = (unsigned char*)alloc(E_TOTAL);
    int* counts = (int*)alloc((size_t)(B_G * N0) * 4);
    int* indptr = (int*)alloc((size_t)(B_G * N0) * 4);
    int* cursor = (int*)alloc((size_t)(B_G * N0) * 4);
    int* srclist = (int*)alloc((size_t)E_TOTAL * 4);
    float* score = (float*)alloc((size_t)(B_G * N0) * 4);
    int* invbuf[2] = {(int*)alloc((size_t)(B_G * N0) * 4), (int*)alloc((size_t)(B_G * N0) * 4)};
    int* kglob = (int*)alloc((size_t)(B_G * K1) * 4);
    float* kval = (float*)alloc((size_t)(B_G * K1) * 4);
    float* g = (float*)alloc((size_t)B_G * 256 * 4);

    const int EGRID = (E_TOTAL + 255) / 256;
    init_all<<<EGRID, 256, 0, stream>>>(es, ed, cur_src, cur_dst, valid, g, counts, invbuf[0]);

    int nper[4] = {N0, K1, K2, K3};
    const float* xin = x0;
    for (int l = 0; l < 3; l++) {
        int n = nper[l], k = nper[l + 1];
        int n_nodes = B_G * n;
        int nk = B_G * k;
        int* invA = invbuf[l & 1];
        int* invB = invbuf[(l + 1) & 1];
        if (l == 0)
            count_edges<<<EGRID, 256, 0, stream>>>(cur_dst, valid, counts);
        scan_graph<<<B_G, 512, 0, stream>>>(counts, indptr, cursor, n);
        fill_srclist<<<EGRID, 256, 0, stream>>>(cur_src, cur_dst, valid, cursor, srclist);
        aggregate<<<n_nodes / 4, 256, 0, stream>>>(xin, indptr, counts, srclist, bufA, n_nodes);
        transform<<<n_nodes / 64, 256, 0, stream>>>(bufA, xin, Wrel[l], Wroot[l], brel[l],
                                                    pvec[l], bufA, score);
        topk_kernel<<<B_G, 256, 0, stream>>>(score, invA, kglob, kval, n, k);
        gather_kernel<<<(nk + 3) / 4, 256, 0, stream>>>(bufA, kglob, kval, bufX, nk);
        readout_kernel<<<B_G, 512, 0, stream>>>(bufX, g, k);
        if (l < 2) {
            prep_next<<<(B_G * k + 255) / 256, 256, 0, stream>>>(counts, invB, B_G * k);
            remap_count<<<EGRID, 256, 0, stream>>>(cur_src, cur_dst, valid, invA, counts);
        }
        xin = bufX;
    }
    mlp_kernel<<<B_G, 128, 0, stream>>>(g, W1, b1, W2, b2, W3, b3, (float*)d_out);
}

// Round 4
// 489.682 us; speedup vs baseline: 1.8924x; 1.1814x over previous
//
#include <hip/hip_runtime.h>
#include <hip/hip_bf16.h>
#include <math.h>

#define B_G   128
#define N0    512
#define DEG   8
#define CCH   128
#define EPG   (N0*DEG)            // 4096 edges per graph (fixed slab)
#define E_TOTAL (B_G*EPG)
#define K1    410
#define K2    328
#define K3    263
#define NCLS  10

using bf16x8 = __attribute__((ext_vector_type(8))) __bf16;
using f32x4  = __attribute__((ext_vector_type(4))) float;
typedef unsigned short ushort;
typedef unsigned int uint;

__device__ __forceinline__ ushort f2b(float f) {
    uint u = __float_as_uint(f);
    u += 0x7fffu + ((u >> 16) & 1u);      // RNE
    return (ushort)(u >> 16);
}
__device__ __forceinline__ float b2f(ushort h) {
    return __uint_as_float(((uint)h) << 16);
}
// split fp32 -> (hi, lo) bf16 pair;  v ~= hi + lo  (error ~2^-17 rel)
__device__ __forceinline__ void split2(float v, ushort& hi, ushort& lo) {
    hi = f2b(v);
    lo = f2b(v - b2f(hi));
}

// ---------------- convert x0 fp32 -> hi/lo bf16 pair arrays ----------------
__global__ void convert_x(const float* __restrict__ x0, ushort* __restrict__ xh,
                          ushort* __restrict__ xl, int n4) {
    int i = blockIdx.x * 256 + threadIdx.x;   // one float4 per thread
    if (i >= n4) return;
    float4 v = ((const float4*)x0)[i];
    ushort h0, l0, h1, l1, h2, l2, h3, l3;
    split2(v.x, h0, l0); split2(v.y, h1, l1);
    split2(v.z, h2, l2); split2(v.w, h3, l3);
    ((uint2*)xh)[i] = make_uint2((uint)h0 | ((uint)h1 << 16), (uint)h2 | ((uint)h3 << 16));
    ((uint2*)xl)[i] = make_uint2((uint)l0 | ((uint)l1 << 16), (uint)l2 | ((uint)l3 << 16));
}

// ---------------- pack weights into per-lane MFMA fragment layout (hi/lo) ----------------
// Bp[layer][ks][cf][lane][j] ; k = ks*32 + (lane>>4)*8 + j ; c = cf*16 + (lane&15)
__global__ void pack_weights(const float* __restrict__ Wrel0, const float* __restrict__ Wroot0,
                             const float* __restrict__ Wrel1, const float* __restrict__ Wroot1,
                             const float* __restrict__ Wrel2, const float* __restrict__ Wroot2,
                             ushort* __restrict__ Bph, ushort* __restrict__ Bpl) {
    int idx = blockIdx.x * 256 + threadIdx.x;
    if (idx >= 3 * 32768) return;
    int layer = idx >> 15, rem = idx & 32767;
    int j = rem & 7, lane = (rem >> 3) & 63, cf = (rem >> 9) & 7, ks = rem >> 12;
    int k = ks * 32 + (lane >> 4) * 8 + j;
    int c = cf * 16 + (lane & 15);
    const float* Wrel  = layer == 0 ? Wrel0  : layer == 1 ? Wrel1  : Wrel2;
    const float* Wroot = layer == 0 ? Wroot0 : layer == 1 ? Wroot1 : Wroot2;
    float v = (k < 128) ? Wrel[k * 128 + c] : Wroot[(k - 128) * 128 + c];
    ushort hi, lo; split2(v, hi, lo);
    Bph[idx] = hi; Bpl[idx] = lo;
}

// ---------------- init: copy edges, valid=1, zero g, zero counts, inv=-1 ----------------
__global__ void init_all(const int* __restrict__ es, const int* __restrict__ ed,
                         int* __restrict__ cs, int* __restrict__ cd,
                         unsigned char* __restrict__ valid, float* __restrict__ g,
                         int* __restrict__ counts, int* __restrict__ inv) {
    int e = blockIdx.x * 256 + threadIdx.x;
    if (e < E_TOTAL) { cs[e] = es[e]; cd[e] = ed[e]; valid[e] = 1; }
    if (e < B_G * N0) { counts[e] = 0; inv[e] = -1; }
    if (e < B_G * 256) g[e] = 0.f;
}

// ---------------- layer-0 edge count ----------------
__global__ void count_edges(const int* __restrict__ dst, const unsigned char* __restrict__ valid,
                            int* __restrict__ counts) {
    int e = blockIdx.x * 256 + threadIdx.x;
    if (e < E_TOTAL && valid[e]) atomicAdd(&counts[dst[e]], 1);
}

// ---------------- per-graph exclusive scan (n <= 512), one block per graph ----------------
__global__ __launch_bounds__(512) void scan_graph(const int* __restrict__ counts,
                                                  int* __restrict__ indptr,
                                                  int* __restrict__ cursor, int n) {
    int b = blockIdx.x, tid = threadIdx.x;
    __shared__ int s[512];
    s[tid] = (tid < n) ? counts[b * n + tid] : 0;
    __syncthreads();
    for (int off = 1; off < 512; off <<= 1) {
        int v = (tid >= off) ? s[tid - off] : 0;
        __syncthreads();
        s[tid] += v;
        __syncthreads();
    }
    if (tid < n) {
        int pre = tid ? s[tid - 1] : 0;
        int ip = b * EPG + pre;
        indptr[b * n + tid] = ip;
        cursor[b * n + tid] = ip;
    }
}

__global__ void fill_srclist(const int* __restrict__ src, const int* __restrict__ dst,
                             const unsigned char* __restrict__ valid,
                             int* __restrict__ cursor, int* __restrict__ srclist) {
    int e = blockIdx.x * 256 + threadIdx.x;
    if (e < E_TOTAL && valid[e]) {
        int pos = atomicAdd(&cursor[dst[e]], 1);
        srclist[pos] = src[e];
    }
}

// ---------------- aggregation: one wave per dst node, hi/lo in, hi/lo out, fp32 accum ----------------
__global__ void aggregate(const ushort* __restrict__ xh, const ushort* __restrict__ xl,
                          const int* __restrict__ indptr, const int* __restrict__ counts,
                          const int* __restrict__ srclist,
                          ushort* __restrict__ ah, ushort* __restrict__ al, int n_nodes) {
    int wid = (blockIdx.x * 256 + threadIdx.x) >> 6;
    int lane = threadIdx.x & 63;
    if (wid >= n_nodes) return;
    float s0 = 0.f, s1 = 0.f;
    int beg = indptr[wid], end = beg + counts[wid];
    for (int j = beg; j < end; j++) {
        int s = srclist[j];
        uint h = ((const uint*)(xh + (size_t)s * CCH))[lane];
        uint l = ((const uint*)(xl + (size_t)s * CCH))[lane];
        s0 += __uint_as_float(h << 16) + __uint_as_float(l << 16);
        s1 += __uint_as_float(h & 0xffff0000u) + __uint_as_float(l & 0xffff0000u);
    }
    ushort h0, l0, h1, l1;
    split2(s0, h0, l0); split2(s1, h1, l1);
    ((uint*)(ah + (size_t)wid * CCH))[lane] = (uint)h0 | ((uint)h1 << 16);
    ((uint*)(al + (size_t)wid * CCH))[lane] = (uint)l0 | ((uint)l1 << 16);
}

// ---------------- bf16x3 MFMA transform + fused score ----------------
//   h = relu([agg|x] @ [Wrel;Wroot] + brel) ; score = tanh(h.p/||p||)
// block = 256 thr (4 waves); each wave owns 32 rows (2 frags) x 128 cols. No LDS.
// A*B ~= Ah*Bh + Ah*Bl + Al*Bh  (fp32 accumulate)
__global__ __launch_bounds__(256) void transform_mfma(
        const ushort* __restrict__ agg_hi, const ushort* __restrict__ agg_lo,
        const ushort* __restrict__ x_hi, const ushort* __restrict__ x_lo,
        const ushort* __restrict__ Bph, const ushort* __restrict__ Bpl,
        const float* __restrict__ brel, const float* __restrict__ pvec,
        ushort* __restrict__ h_hi, ushort* __restrict__ h_lo, float* __restrict__ score) {
    int tid = threadIdx.x;
    int wave = tid >> 6, lane = tid & 63;
    int r = lane & 15, kb = lane >> 4;
    int rows0 = blockIdx.x * 128 + wave * 32;

    f32x4 acc[2][8];
#pragma unroll
    for (int rf = 0; rf < 2; rf++)
#pragma unroll
        for (int cf = 0; cf < 8; cf++) acc[rf][cf] = (f32x4)(0.f);

    const bf16x8* Bh = (const bf16x8*)Bph;
    const bf16x8* Bl = (const bf16x8*)Bpl;

#pragma unroll
    for (int ks = 0; ks < 8; ks++) {
        const ushort* Ah = (ks < 4) ? agg_hi : x_hi;
        const ushort* Al = (ks < 4) ? agg_lo : x_lo;
        int kofs = (ks & 3) * 32 + kb * 8;
        bf16x8 a_hi[2], a_lo[2];
#pragma unroll
        for (int rf = 0; rf < 2; rf++) {
            size_t rowbase = (size_t)(rows0 + rf * 16 + r) * CCH + kofs;
            a_hi[rf] = *(const bf16x8*)&Ah[rowbase];
            a_lo[rf] = *(const bf16x8*)&Al[rowbase];
        }
#pragma unroll
        for (int cf = 0; cf < 8; cf++) {
            bf16x8 bh = Bh[(ks * 8 + cf) * 64 + lane];
            bf16x8 bl = Bl[(ks * 8 + cf) * 64 + lane];
#pragma unroll
            for (int rf = 0; rf < 2; rf++) {
                acc[rf][cf] = __builtin_amdgcn_mfma_f32_16x16x32_bf16(a_hi[rf], bl, acc[rf][cf], 0, 0, 0);
                acc[rf][cf] = __builtin_amdgcn_mfma_f32_16x16x32_bf16(a_lo[rf], bh, acc[rf][cf], 0, 0, 0);
                acc[rf][cf] = __builtin_amdgcn_mfma_f32_16x16x32_bf16(a_hi[rf], bh, acc[rf][cf], 0, 0, 0);
            }
        }
    }

    // epilogue: bias+relu (fp32), hi/lo store, fused score
    float pv[8], bb[8], q = 0.f;
#pragma unroll
    for (int cf = 0; cf < 8; cf++) {
        pv[cf] = pvec[cf * 16 + r];
        bb[cf] = brel[cf * 16 + r];
        q += pv[cf] * pv[cf];
    }
    float dots[2][4] = {{0.f,0.f,0.f,0.f},{0.f,0.f,0.f,0.f}};
#pragma unroll
    for (int rf = 0; rf < 2; rf++) {
#pragma unroll
        for (int cf = 0; cf < 8; cf++) {
#pragma unroll
            for (int reg = 0; reg < 4; reg++) {
                float v = acc[rf][cf][reg] + bb[cf];
                v = v > 0.f ? v : 0.f;
                int row = rows0 + rf * 16 + kb * 4 + reg;
                ushort hi, lo; split2(v, hi, lo);
                h_hi[(size_t)row * CCH + cf * 16 + r] = hi;
                h_lo[(size_t)row * CCH + cf * 16 + r] = lo;
                dots[rf][reg] += v * pv[cf];
            }
        }
    }
#pragma unroll
    for (int off = 1; off < 16; off <<= 1) {
        q += __shfl_xor(q, off);
#pragma unroll
        for (int rf = 0; rf < 2; rf++)
#pragma unroll
            for (int reg = 0; reg < 4; reg++)
                dots[rf][reg] += __shfl_xor(dots[rf][reg], off);
    }
    if (r == 0) {
        float inv_norm = rsqrtf(q);
#pragma unroll
        for (int rf = 0; rf < 2; rf++)
#pragma unroll
            for (int reg = 0; reg < 4; reg++)
                score[rows0 + rf * 16 + kb * 4 + reg] = tanhf(dots[rf][reg] * inv_norm);
    }
}

// ---------------- top-k per graph: bitonic sort of 512 packed keys ----------------
__global__ __launch_bounds__(256) void topk_kernel(const float* __restrict__ score,
                                                   int* __restrict__ inv,
                                                   int* __restrict__ kglob,
                                                   float* __restrict__ kval, int n, int k) {
    int b = blockIdx.x;
    __shared__ unsigned long long keys[512];
    int tid = threadIdx.x;
    for (int s = tid; s < 512; s += 256) {
        unsigned long long key = 0ull;   // sorts below all real scores
        if (s < n) {
            float v = score[b * n + s];
            unsigned u = __float_as_uint(v);
            u = (u & 0x80000000u) ? ~u : (u | 0x80000000u);   // orderable
            key = ((unsigned long long)u << 32) | (unsigned)(~s); // ties -> lower idx first
        }
        keys[s] = key;
    }
    __syncthreads();
    for (int kk2 = 2; kk2 <= 512; kk2 <<= 1) {
        for (int j = kk2 >> 1; j > 0; j >>= 1) {
            for (int s = tid; s < 512; s += 256) {
                int sxj = s ^ j;
                if (sxj > s) {
                    unsigned long long a = keys[s], c = keys[sxj];
                    bool descRegion = ((s & kk2) == 0);
                    bool doSwap = descRegion ? (a < c) : (a > c);
                    if (doSwap) { keys[s] = c; keys[sxj] = a; }
                }
            }
            __syncthreads();
        }
    }
    for (int j = tid; j < k; j += 256) {
        unsigned long long key = keys[j];
        int node = (int)(~(unsigned)key);
        float v = score[b * n + node];
        int newid = b * k + j;
        kglob[newid] = b * n + node;
        kval[newid] = v;
        inv[b * n + node] = newid;
    }
}

// ---------------- gather+scale kept rows (hi/lo -> hi/lo) ----------------
__global__ void gather_kernel(const ushort* __restrict__ hh, const ushort* __restrict__ hl,
                              const int* __restrict__ kglob, const float* __restrict__ kval,
                              ushort* __restrict__ xh, ushort* __restrict__ xl, int nk) {
    int wid = (blockIdx.x * 256 + threadIdx.x) >> 6;
    int lane = threadIdx.x & 63;
    if (wid >= nk) return;
    int gsrc = kglob[wid];
    float v = kval[wid];
    uint h = ((const uint*)(hh + (size_t)gsrc * CCH))[lane];
    uint l = ((const uint*)(hl + (size_t)gsrc * CCH))[lane];
    float c0 = (__uint_as_float(h << 16) + __uint_as_float(l << 16)) * v;
    float c1 = (__uint_as_float(h & 0xffff0000u) + __uint_as_float(l & 0xffff0000u)) * v;
    ushort h0, l0, h1, l1;
    split2(c0, h0, l0); split2(c1, h1, l1);
    ((uint*)(xh + (size_t)wid * CCH))[lane] = (uint)h0 | ((uint)h1 << 16);
    ((uint*)(xl + (size_t)wid * CCH))[lane] = (uint)l0 | ((uint)l1 << 16);
}

// ---------------- prep next layer: zero counts, inv=-1 ----------------
__global__ void prep_next(int* __restrict__ counts, int* __restrict__ inv, int n) {
    int i = blockIdx.x * 256 + threadIdx.x;
    if (i < n) { counts[i] = 0; inv[i] = -1; }
}

// ---------------- fused remap edges + count for next layer ----------------
__global__ void remap_count(int* __restrict__ src, int* __restrict__ dst,
                            unsigned char* __restrict__ valid, const int* __restrict__ inv,
                            int* __restrict__ counts) {
    int e = blockIdx.x * 256 + threadIdx.x;
    if (e >= E_TOTAL) return;
    if (!valid[e]) return;
    int s = inv[src[e]], d = inv[dst[e]];
    if ((s | d) < 0) { valid[e] = 0; }
    else { src[e] = s; dst[e] = d; atomicAdd(&counts[d], 1); }
}

// ---------------- readout: gmp || gap (hi/lo input), accumulated into g ----------------
__global__ __launch_bounds__(512) void readout_kernel(const ushort* __restrict__ xh,
                                                      const ushort* __restrict__ xl,
                                                      float* __restrict__ g, int k) {
    int b = blockIdx.x;
    int c = threadIdx.x & 127;
    int q = threadIdx.x >> 7;
    float mx = -1e30f, sm = 0.f;
    for (int j = q; j < k; j += 4) {
        size_t idx = ((size_t)b * k + j) * CCH + c;
        float v = b2f(xh[idx]) + b2f(xl[idx]);
        mx = fmaxf(mx, v); sm += v;
    }
    __shared__ float smx[4][128], ssm[4][128];
    smx[q][c] = mx; ssm[q][c] = sm;
    __syncthreads();
    if (q == 0) {
        mx = fmaxf(fmaxf(smx[0][c], smx[1][c]), fmaxf(smx[2][c], smx[3][c]));
        sm = ssm[0][c] + ssm[1][c] + ssm[2][c] + ssm[3][c];
        g[b * 256 + c] += mx;
        g[b * 256 + 128 + c] += sm / (float)k;
    }
}

// ---------------- final MLP + log_softmax ----------------
__global__ __launch_bounds__(128) void mlp_kernel(const float* __restrict__ g,
        const float* __restrict__ W1, const float* __restrict__ b1,
        const float* __restrict__ W2, const float* __restrict__ b2,
        const float* __restrict__ W3, const float* __restrict__ b3,
        float* __restrict__ out) {
    int b = blockIdx.x, t = threadIdx.x;
    __shared__ float gs[256], h1[128], h2[64], lg[10];
    gs[t] = g[b * 256 + t];
    gs[128 + t] = g[b * 256 + 128 + t];
    __syncthreads();
    {
        float a = b1[t];
        for (int c = 0; c < 256; c++) a += gs[c] * W1[c * 128 + t];
        h1[t] = fmaxf(a, 0.f);
    }
    __syncthreads();
    if (t < 64) {
        float a = b2[t];
        for (int c = 0; c < 128; c++) a += h1[c] * W2[c * 64 + t];
        h2[t] = fmaxf(a, 0.f);
    }
    __syncthreads();
    if (t < 10) {
        float a = b3[t];
        for (int c = 0; c < 64; c++) a += h2[c] * W3[c * 10 + t];
        lg[t] = a;
    }
    __syncthreads();
    if (t < 10) {
        float m = lg[0];
        for (int i = 1; i < 10; i++) m = fmaxf(m, lg[i]);
        float s = 0.f;
        for (int i = 0; i < 10; i++) s += expf(lg[i] - m);
        out[b * 10 + t] = lg[t] - m - logf(s);
    }
}

// ---------------- host ----------------
extern "C" void kernel_launch(void* const* d_in, const int* in_sizes, int n_in,
                              void* d_out, int out_size, void* d_ws, size_t ws_size,
                              hipStream_t stream) {
    (void)in_sizes; (void)n_in; (void)out_size; (void)ws_size;
    const float* x0 = (const float*)d_in[0];
    const int* es = (const int*)d_in[1];
    const int* ed = (const int*)d_in[2];
    const float* Wroot[3] = {(const float*)d_in[3], (const float*)d_in[7], (const float*)d_in[11]};
    const float* Wrel[3]  = {(const float*)d_in[4], (const float*)d_in[8], (const float*)d_in[12]};
    const float* brel[3]  = {(const float*)d_in[5], (const float*)d_in[9], (const float*)d_in[13]};
    const float* pvec[3]  = {(const float*)d_in[6], (const float*)d_in[10], (const float*)d_in[14]};
    const float* W1 = (const float*)d_in[15];
    const float* b1 = (const float*)d_in[16];
    const float* W2 = (const float*)d_in[17];
    const float* b2 = (const float*)d_in[18];
    const float* W3 = (const float*)d_in[19];
    const float* b3 = (const float*)d_in[20];

    size_t off = 0;
    char* base = (char*)d_ws;
    auto alloc = [&](size_t bytes) -> void* {
        void* p = base + off;
        off += (bytes + 255) & ~(size_t)255;
        return p;
    };
    const size_t FEAT = (size_t)(B_G * N0) * CCH * 2;   // bf16 plane
    ushort* xb_hi  = (ushort*)alloc(FEAT);   // layer-input features hi
    ushort* xb_lo  = (ushort*)alloc(FEAT);   // layer-input features lo
    ushort* agg_hi = (ushort*)alloc(FEAT);   // aggregation hi (reused as h hi)
    ushort* agg_lo = (ushort*)alloc(FEAT);   // aggregation lo (reused as h lo)
    ushort* Bph = (ushort*)alloc((size_t)3 * 32768 * 2); // packed weights hi
    ushort* Bpl = (ushort*)alloc((size_t)3 * 32768 * 2); // packed weights lo
    int* cur_src = (int*)alloc((size_t)E_TOTAL * 4);
    int* cur_dst = (int*)alloc((size_t)E_TOTAL * 4);
    unsigned char* valid = (unsigned char*)alloc(E_TOTAL);
    int* counts = (int*)alloc((size_t)(B_G * N0) * 4);
    int* indptr = (int*)alloc((size_t)(B_G * N0) * 4);
    int* cursor = (int*)alloc((size_t)(B_G * N0) * 4);
    int* srclist = (int*)alloc((size_t)E_TOTAL * 4);
    float* score = (float*)alloc((size_t)(B_G * N0) * 4);
    int* invbuf[2] = {(int*)alloc((size_t)(B_G * N0) * 4), (int*)alloc((size_t)(B_G * N0) * 4)};
    int* kglob = (int*)alloc((size_t)(B_G * K1) * 4);
    float* kval = (float*)alloc((size_t)(B_G * K1) * 4);
    float* g = (float*)alloc((size_t)B_G * 256 * 4);

    const int EGRID = (E_TOTAL + 255) / 256;
    convert_x<<<(B_G * N0 * CCH / 4 + 255) / 256, 256, 0, stream>>>(x0, xb_hi, xb_lo,
                                                                    B_G * N0 * CCH / 4);
    pack_weights<<<(3 * 32768 + 255) / 256, 256, 0, stream>>>(
        Wrel[0], Wroot[0], Wrel[1], Wroot[1], Wrel[2], Wroot[2], Bph, Bpl);
    init_all<<<EGRID, 256, 0, stream>>>(es, ed, cur_src, cur_dst, valid, g, counts, invbuf[0]);

    int nper[4] = {N0, K1, K2, K3};
    for (int l = 0; l < 3; l++) {
        int n = nper[l], k = nper[l + 1];
        int n_nodes = B_G * n;
        int nk = B_G * k;
        int* invA = invbuf[l & 1];
        int* invB = invbuf[(l + 1) & 1];
        if (l == 0)
            count_edges<<<EGRID, 256, 0, stream>>>(cur_dst, valid, counts);
        scan_graph<<<B_G, 512, 0, stream>>>(counts, indptr, cursor, n);
        fill_srclist<<<EGRID, 256, 0, stream>>>(cur_src, cur_dst, valid, cursor, srclist);
        aggregate<<<n_nodes / 4, 256, 0, stream>>>(xb_hi, xb_lo, indptr, counts, srclist,
                                                   agg_hi, agg_lo, n_nodes);
        // h overwrites agg in place (each wave reads its 32 rows fully before writing them)
        transform_mfma<<<n_nodes / 128, 256, 0, stream>>>(
            agg_hi, agg_lo, xb_hi, xb_lo,
            Bph + (size_t)l * 32768, Bpl + (size_t)l * 32768,
            brel[l], pvec[l], agg_hi, agg_lo, score);
        topk_kernel<<<B_G, 256, 0, stream>>>(score, invA, kglob, kval, n, k);
        gather_kernel<<<(nk + 3) / 4, 256, 0, stream>>>(agg_hi, agg_lo, kglob, kval,
                                                        xb_hi, xb_lo, nk);
        readout_kernel<<<B_G, 512, 0, stream>>>(xb_hi, xb_lo, g, k);
        if (l < 2) {
            prep_next<<<(B_G * k + 255) / 256, 256, 0, stream>>>(counts, invB, B_G * k);
            remap_count<<<EGRID, 256, 0, stream>>>(cur_src, cur_dst, valid, invA, counts);
        }
    }
    mlp_kernel<<<B_G, 128, 0, stream>>>(g, W1, b1, W2, b2, W3, b3, (float*)d_out);
}